// Round 11
// baseline (39313.705 us; speedup 1.0000x reference)
//
#include <hip/hip_runtime.h>
#include <hip/hip_bf16.h>

#define B_ 512
#define T_ 128
#define DIN_ 256
#define H_ 512
#define KP_ 520             // LDS stride (bf16) K=512 weights
#define KP0_ 264            // LDS stride K=256 (wih0)
#define OUT_MAIN ((size_t)B_ * T_ * H_)
#define GISLAB 12288
#define MAGICTOK 0x5AD0BEEF

// ws byte offsets
#define OFF_H1L2 2097152ull
#define OFF_H0L3 4194304ull
#define OFF_H1L3 6291456ull
#define OFF_GI1  8388608ull
#define OFF_FLG  16777216ull

typedef __attribute__((ext_vector_type(8))) short short8;
typedef __attribute__((ext_vector_type(4))) float f32x4;

__device__ __forceinline__ float sigm(float v) { return 1.0f / (1.0f + __expf(-v)); }

__device__ __forceinline__ unsigned short f2bf(float f) {
    union { __hip_bfloat16 b; unsigned short u; } c;
    c.b = __float2bfloat16(f);
    return c.u;
}

__device__ __forceinline__ short8 cvt8v(f32x4 u, f32x4 v) {
    short8 o;
    o[0] = (short)f2bf(u[0]); o[1] = (short)f2bf(u[1]);
    o[2] = (short)f2bf(u[2]); o[3] = (short)f2bf(u[3]);
    o[4] = (short)f2bf(v[0]); o[5] = (short)f2bf(v[1]);
    o[6] = (short)f2bf(v[2]); o[7] = (short)f2bf(v[3]);
    return o;
}

// 16B load: LCL=true -> sc0 (L1 bypass, same-XCD L2); LCL=false -> sc0 sc1 (coherent point)
template<bool LCL>
__device__ __forceinline__ short8 ldh(const __hip_bfloat16* p) {
    short8 r;
    if (LCL) asm volatile("global_load_dwordx4 %0, %1, off sc0"     : "=v"(r) : "v"(p));
    else     asm volatile("global_load_dwordx4 %0, %1, off sc0 sc1" : "=v"(r) : "v"(p));
    return r;
}
#define VMWAIT(N) do { asm volatile("s_waitcnt vmcnt(" #N ")" ::: "memory"); \
                       __builtin_amdgcn_sched_barrier(0); } while (0)

__device__ __forceinline__ int ld_flag_l2(const int* p) {
    int r;
    asm volatile("global_load_dword %0, %1, off sc0\n\ts_waitcnt vmcnt(0)"
                 : "=v"(r) : "v"(p) : "memory");
    return r;
}

__device__ __forceinline__ unsigned long long load_sc8(const __hip_bfloat16* p) {
    return __hip_atomic_load((const unsigned long long*)p, __ATOMIC_RELAXED, __HIP_MEMORY_SCOPE_AGENT);
}
__device__ __forceinline__ void store_sc8u(__hip_bfloat16* p, unsigned long long v) {
    __hip_atomic_store((unsigned long long*)p, v, __ATOMIC_RELAXED, __HIP_MEMORY_SCOPE_AGENT);
}
__device__ __forceinline__ void store_sc8(__hip_bfloat16* p, f32x4 h4) {
    union { unsigned short s[4]; unsigned long long u; } r;
    r.s[0] = f2bf(h4[0]); r.s[1] = f2bf(h4[1]);
    r.s[2] = f2bf(h4[2]); r.s[3] = f2bf(h4[3]);
    store_sc8u(p, r.u);
}

__device__ __forceinline__ f32x4 unpk(unsigned long long u) {
    f32x4 r;
    r[0] = __uint_as_float((unsigned)(u & 0xffffull) << 16);
    r[1] = __uint_as_float((unsigned)((u >> 16) & 0xffffull) << 16);
    r[2] = __uint_as_float((unsigned)((u >> 32) & 0xffffull) << 16);
    r[3] = __uint_as_float((unsigned)((u >> 48) & 0xffffull) << 16);
    return r;
}

// Poll with guaranteed termination: local (sc0) poll escalates to agent flag on timeout.
__device__ __forceinline__ void pollf(const int* lf, const int* gf, bool lcl) {
    int it = 0;
    const int* p = lcl ? lf : gf;
    for (;;) {
        int v = lcl ? ld_flag_l2(p)
                    : __hip_atomic_load(p, __ATOMIC_RELAXED, __HIP_MEMORY_SCOPE_AGENT);
        if (v) return;
        __builtin_amdgcn_s_sleep(1);
        if (lcl && ++it >= 2048) { lcl = false; p = gf; }
    }
}

__global__ void init_kernel(int* __restrict__ flg)
{
    int i = blockIdx.x * blockDim.x + threadIdx.x;
    int stride = gridDim.x * blockDim.x;
    for (int k = i; k < 66560; k += stride)
        __hip_atomic_store(&flg[k], 0, __ATOMIC_RELAXED, __HIP_MEMORY_SCOPE_AGENT);
}

// acc: 0,1=r  2,3=z  NB,NB+1=n
template<int KP, int NB>
__device__ __forceinline__ void chunk6(const __hip_bfloat16* wl, int l15, int kg, int kc,
                                       short8 bf, f32x4* acc) {
    #pragma unroll
    for (int g = 0; g < 3; ++g) {
        const int ai = (g == 2) ? NB : g * 2;
        #pragma unroll
        for (int jh = 0; jh < 2; ++jh) {
            short8 wf = *(const short8*)&wl[(size_t)(g * 32 + jh * 16 + l15) * KP + kc * 32 + kg];
            acc[ai + jh] = __builtin_amdgcn_mfma_f32_16x16x32_bf16(wf, bf, acc[ai + jh], 0, 0, 0);
        }
    }
}

template<bool LCL, int NB>
__device__ __forceinline__ void gather16(const __hip_bfloat16* tb, const __hip_bfloat16* wl,
                                         int l15, int kg, bool z, f32x4* acc)
{
    const short8 zed = {0,0,0,0,0,0,0,0};
    short8 A0,A1,A2,A3,B0,B1,B2,B3;
    A0=ldh<LCL>(tb);      A1=ldh<LCL>(tb+512);  A2=ldh<LCL>(tb+1024); A3=ldh<LCL>(tb+1536);
    B0=ldh<LCL>(tb+2048); B1=ldh<LCL>(tb+2560); B2=ldh<LCL>(tb+3072); B3=ldh<LCL>(tb+3584);
    VMWAIT(4);
    chunk6<KP_,NB>(wl,l15,kg,0, z?zed:A0, acc); chunk6<KP_,NB>(wl,l15,kg,1, z?zed:A1, acc);
    chunk6<KP_,NB>(wl,l15,kg,2, z?zed:A2, acc); chunk6<KP_,NB>(wl,l15,kg,3, z?zed:A3, acc);
    A0=ldh<LCL>(tb+4096); A1=ldh<LCL>(tb+4608); A2=ldh<LCL>(tb+5120); A3=ldh<LCL>(tb+5632);
    VMWAIT(4);
    chunk6<KP_,NB>(wl,l15,kg,4, z?zed:B0, acc); chunk6<KP_,NB>(wl,l15,kg,5, z?zed:B1, acc);
    chunk6<KP_,NB>(wl,l15,kg,6, z?zed:B2, acc); chunk6<KP_,NB>(wl,l15,kg,7, z?zed:B3, acc);
    B0=ldh<LCL>(tb+6144); B1=ldh<LCL>(tb+6656); B2=ldh<LCL>(tb+7168); B3=ldh<LCL>(tb+7680);
    VMWAIT(4);
    chunk6<KP_,NB>(wl,l15,kg,8,  z?zed:A0, acc); chunk6<KP_,NB>(wl,l15,kg,9,  z?zed:A1, acc);
    chunk6<KP_,NB>(wl,l15,kg,10, z?zed:A2, acc); chunk6<KP_,NB>(wl,l15,kg,11, z?zed:A3, acc);
    VMWAIT(0);
    chunk6<KP_,NB>(wl,l15,kg,12, z?zed:B0, acc); chunk6<KP_,NB>(wl,l15,kg,13, z?zed:B1, acc);
    chunk6<KP_,NB>(wl,l15,kg,14, z?zed:B2, acc); chunk6<KP_,NB>(wl,l15,kg,15, z?zed:B3, acc);
}

// 256 blocks x 512 threads. bid decode (XCD = bid%8 heuristic, validated at runtime):
//   r8<4:  k8<16 -> R0(bt=r8, jp=k8); k8>=16 -> G1(bt=r8, jp=k8-16)     [XCD r8]
//   r8>=4: k8<16 -> R1(bt=r8-4, jp=k8); else dummy (exit)               [XCD r8]
// R0: gi0 (local, x + wih0 in LDS) + gh0 + fuse -> h0. G1: gi1 = h0 @ wih1^T.
// R1: gh1 + gi1 slab + fuse -> out. h rings dual-published (L2 plain + L3 agent);
// consumers pick transport per startup validation; every local poll escalates to agent.
__global__ __launch_bounds__(512) void gru_x(
    const float* __restrict__ x, const int* __restrict__ is_init,
    const float* __restrict__ h_in,
    const float* __restrict__ wih0, const float* __restrict__ whh0,
    const float* __restrict__ bih0, const float* __restrict__ bhh0,
    const float* __restrict__ wih1, const float* __restrict__ whh1,
    const float* __restrict__ bih1, const float* __restrict__ bhh1,
    char* __restrict__ ws, float* __restrict__ out)
{
    __shared__ __hip_bfloat16 wsh[96 * KP_ + 96 * KP0_];   // 150528 B
    __shared__ int s_usel2;

    const int bid = blockIdx.x;
    const int r8 = bid & 7;
    const int k8 = bid >> 3;
    int stage, bt, jp;
    if (r8 < 4) { bt = r8; if (k8 < 16) { stage = 0; jp = k8; } else { stage = 2; jp = k8 - 16; } }
    else        { if (k8 >= 16) return; stage = 1; bt = r8 - 4; jp = k8; }

    __hip_bfloat16* h0l2 = (__hip_bfloat16*)ws;
    __hip_bfloat16* h1l2 = (__hip_bfloat16*)(ws + OFF_H1L2);
    __hip_bfloat16* h0l3 = (__hip_bfloat16*)(ws + OFF_H0L3);
    __hip_bfloat16* h1l3 = (__hip_bfloat16*)(ws + OFF_H1L3);
    __hip_bfloat16* gi1  = (__hip_bfloat16*)(ws + OFF_GI1);
    int* flg      = (int*)(ws + OFF_FLG);
    int* gfh0     = flg;                // [(t*4+bt)*16+jp]
    int* gfh1     = flg + 8192;
    int* gfgi1    = flg + 16384;
    int* lfh0     = flg + 24576;        // [bt*4096 + t*16 + jp]
    int* lfh1     = flg + 40960;
    int* blkready = flg + 57344;        // [256]
    int* xcc_tab  = flg + 57600;        // [256]
    int* tokl2    = flg + 57856;        // [256*32]

    const int tid = threadIdx.x;
    const int lane = tid & 63;
    const int w = tid >> 6;
    const int l15 = lane & 15;
    const int q = lane >> 4;
    const int kg = q * 8;
    const int qr4 = q * 4;
    const int rb = bt * 128;
    const int jb = jp * 32;
    const int bw = rb + w * 16 + l15;
    const int b16 = bt * 8 + w;

    // ================= startup: clean local flags, token, rendezvous, validate =================
    int myxcc;
    asm volatile("s_getreg_b32 %0, hwreg(HW_REG_XCC_ID)" : "=s"(myxcc));
    myxcc &= 7;
    if (stage == 0 && tid < 128) lfh0[bt * 4096 + tid * 16 + jp] = 0;   // plain: own-L2 clean
    if (stage == 1 && tid < 128) lfh1[bt * 4096 + tid * 16 + jp] = 0;
    if (tid < 32) tokl2[bid * 32 + tid] = (tid == 0) ? MAGICTOK : 0;    // own whole line
    __syncthreads();
    if (tid == 0) {
        asm volatile("s_waitcnt vmcnt(0)" ::: "memory");
        __hip_atomic_store(&xcc_tab[bid], myxcc + 1, __ATOMIC_RELAXED, __HIP_MEMORY_SCOPE_AGENT);
        __hip_atomic_store(&blkready[bid], 1, __ATOMIC_RELAXED, __HIP_MEMORY_SCOPE_AGENT);
        s_usel2 = 1;
    }
    if (w == 0) {
        #pragma unroll
        for (int base = 0; base < 256; base += 64) {
            int b = base + lane;
            bool act = ((b & 7) < 4) || ((b >> 3) < 16);
            int it = 0;
            if (act)
                while (__hip_atomic_load(&blkready[b], __ATOMIC_RELAXED, __HIP_MEMORY_SCOPE_AGENT) == 0) {
                    __builtin_amdgcn_s_sleep(2);
                    if (++it > 60000) break;    // degraded: validation will fail -> agent path
                }
        }
    }
    __syncthreads();
    if (w == 0) {
        int bad = 0;
        if (lane < 16) {
            int p = (stage == 1) ? (lane * 8 + 4 + bt) : (lane * 8 + bt);
            int px = __hip_atomic_load(&xcc_tab[p], __ATOMIC_RELAXED, __HIP_MEMORY_SCOPE_AGENT);
            int tv = ld_flag_l2(&tokl2[p * 32]);
            bad = (px != myxcc + 1) || (tv != MAGICTOK);
        }
        if (__ballot(bad) != 0 && lane == 0) s_usel2 = 0;
    }
    __syncthreads();
    const bool usel2 = (s_usel2 != 0);

    // ================= weight staging =================
    __hip_bfloat16* wlds  = wsh;
    __hip_bfloat16* wlds2 = wsh + 96 * KP_;
    {
        const float* Wsrc = (stage == 0) ? whh0 : (stage == 1) ? whh1 : wih1;
        for (int idx = tid; idx < 96 * 64; idx += 512) {
            int gr = idx >> 6, c8 = idx & 63;
            int grow = (gr >> 5) * H_ + jb + (gr & 31);
            const float* p = Wsrc + (size_t)grow * H_ + c8 * 8;
            *(short8*)&wlds[(size_t)gr * KP_ + c8 * 8] = cvt8v(*(const f32x4*)p, *(const f32x4*)(p + 4));
        }
        if (stage == 0) {
            for (int idx = tid; idx < 96 * 32; idx += 512) {
                int gr = idx >> 5, c8 = idx & 31;
                int grow = (gr >> 5) * H_ + jb + (gr & 31);
                const float* p = wih0 + (size_t)grow * DIN_ + c8 * 8;
                *(short8*)&wlds2[(size_t)gr * KP0_ + c8 * 8] = cvt8v(*(const f32x4*)p, *(const f32x4*)(p + 4));
            }
        }
    }

    // ---- per-lane constants for R stages ----
    f32x4 bR[2], bZ[2], bIN[2], bHN[2], hp[2];
    if (stage < 2) {
        const float* bi = stage ? bih1 : bih0;
        const float* bh = stage ? bhh1 : bhh0;
        #pragma unroll
        for (int jh = 0; jh < 2; ++jh) {
            const int j4 = jb + jh * 16 + qr4;
            bR[jh]  = *(const f32x4*)&bi[j4]          + *(const f32x4*)&bh[j4];
            bZ[jh]  = *(const f32x4*)&bi[H_ + j4]     + *(const f32x4*)&bh[H_ + j4];
            bIN[jh] = *(const f32x4*)&bi[2 * H_ + j4];
            bHN[jh] = *(const f32x4*)&bh[2 * H_ + j4];
            hp[jh]  = *(const f32x4*)&h_in[(size_t)bw * 2 * H_ + (size_t)stage * H_ + j4];
        }
    }
    __syncthreads();

    const short8 zed = {0, 0, 0, 0, 0, 0, 0, 0};

    // ================= main loop =================
    for (int t = 0; t < T_; ++t) {
        f32x4 acc[8];
        #pragma unroll
        for (int i = 0; i < 8; ++i) acc[i] = f32x4{0.f, 0.f, 0.f, 0.f};

        const bool z = (stage == 2) ? false : (is_init[(size_t)bw * T_ + t] != 0);

        // ---- R0 pre-wait work: gi0 = x @ wih0^T (no dependencies) ----
        if (stage == 0) {
            const float* xr = x + ((size_t)bw * T_ + t) * DIN_;
            #pragma unroll
            for (int kc = 0; kc < 8; ++kc) {
                short8 bf = cvt8v(*(const f32x4*)(xr + kc * 32 + kg),
                                  *(const f32x4*)(xr + kc * 32 + kg + 4));
                chunk6<KP0_, 4>(wlds2, l15, kg, kc, bf, acc);
            }
        }

        // ---- dataflow waits ----
        if (w == 0) {
            if (stage == 0) {
                if (lane < 16 && t > 0)
                    pollf(&lfh0[bt * 4096 + (t - 1) * 16 + lane],
                          &gfh0[((t - 1) * 4 + bt) * 16 + lane], usel2);
                else if (lane >= 32 && lane < 48 && t >= 4)
                    pollf(nullptr, &gfgi1[((t - 4) * 4 + bt) * 16 + (lane - 32)], false);
            } else if (stage == 2) {
                if (lane < 16)
                    pollf(&lfh0[bt * 4096 + t * 16 + lane],
                          &gfh0[(t * 4 + bt) * 16 + lane], usel2);
                else if (lane >= 16 && lane < 32 && t >= 4)
                    pollf(nullptr, &gfh1[((t - 4) * 4 + bt) * 16 + (lane - 16)], false);
            } else {
                if (lane < 16 && t > 0)
                    pollf(&lfh1[bt * 4096 + (t - 1) * 16 + lane],
                          &gfh1[((t - 1) * 4 + bt) * 16 + lane], usel2);
                else if (lane == 16)
                    pollf(nullptr, &gfgi1[(t * 4 + bt) * 16 + jp], false);
            }
        }
        __syncthreads();

        if (stage == 0) {
            // ---- gh0 over h0[t-1] ----
            if (t == 0) {
                const float* hr = h_in + (size_t)bw * 2 * H_;
                #pragma unroll
                for (int kc = 0; kc < 16; ++kc) {
                    short8 bf = z ? zed : cvt8v(*(const f32x4*)(hr + kc * 32 + kg),
                                                *(const f32x4*)(hr + kc * 32 + kg + 4));
                    chunk6<KP_, 6>(wlds, l15, kg, kc, bf, acc);
                }
            } else {
                const size_t tboff = (((size_t)((t - 1) & 3) * 32 + b16) * 16) * 512 + lane * 8;
                if (usel2) gather16<true, 6>(h0l2 + tboff, wlds, l15, kg, z, acc);
                else       gather16<false, 6>(h0l3 + tboff, wlds, l15, kg, z, acc);
            }
            // ---- fuse + dual publish h0[t] ----
            const size_t hwoff = (((size_t)(t & 3) * 32 + b16) * 16 + jp) * 512;
            #pragma unroll
            for (int jh = 0; jh < 2; ++jh) {
                const int j4 = jb + jh * 16 + qr4;
                f32x4 hv;
                #pragma unroll
                for (int r = 0; r < 4; ++r) {
                    const float rr = sigm(acc[jh][r] + bR[jh][r]);
                    const float zz = sigm(acc[2 + jh][r] + bZ[jh][r]);
                    const float nn = tanhf(acc[4 + jh][r] + bIN[jh][r] + rr * (acc[6 + jh][r] + bHN[jh][r]));
                    const float hprev = z ? 0.0f : hp[jh][r];
                    hv[r] = (1.0f - zz) * nn + zz * hprev;
                }
                hp[jh] = hv;
                union { unsigned short us[4]; unsigned long long u; } pk;
                pk.us[0] = f2bf(hv[0]); pk.us[1] = f2bf(hv[1]);
                pk.us[2] = f2bf(hv[2]); pk.us[3] = f2bf(hv[3]);
                const int qp = jh * 2 + (q >> 1);
                const size_t eo = hwoff + (qp * 16 + l15) * 8 + (q & 1) * 4;
                *(unsigned long long*)(h0l2 + eo) = pk.u;      // plain -> own L2
                store_sc8u(h0l3 + eo, pk.u);                   // agent -> coherent point
                if (t == T_ - 1)
                    *(f32x4*)&out[OUT_MAIN + (size_t)bw * 2 * H_ + j4] = hv;
            }
            __syncthreads();
            if (tid == 0) {
                lfh0[bt * 4096 + t * 16 + jp] = 1;
                __hip_atomic_store(&gfh0[(t * 4 + bt) * 16 + jp], 1, __ATOMIC_RELAXED, __HIP_MEMORY_SCOPE_AGENT);
            }
        } else if (stage == 2) {
            // ---- G1: gi1[t] = h0[t] @ wih1^T ----
            const size_t tboff = (((size_t)(t & 3) * 32 + b16) * 16) * 512 + lane * 8;
            if (usel2) gather16<true, 4>(h0l2 + tboff, wlds, l15, kg, false, acc);
            else       gather16<false, 4>(h0l3 + tboff, wlds, l15, kg, false, acc);
            __hip_bfloat16* slab = gi1 + (((size_t)(t & 3) * 4 + bt) * 16 + jp) * GISLAB;
            #pragma unroll
            for (int jf = 0; jf < 6; ++jf)
                store_sc8(slab + ((jf * 8 + w) * 64 + lane) * 4, acc[jf]);
            __syncthreads();
            if (tid == 0)
                __hip_atomic_store(&gfgi1[(t * 4 + bt) * 16 + jp], 1, __ATOMIC_RELAXED, __HIP_MEMORY_SCOPE_AGENT);
        } else {
            // ---- R1: slab prefetch + gh1 + fuse + out ----
            const __hip_bfloat16* slab = gi1 + (((size_t)(t & 3) * 4 + bt) * 16 + jp) * GISLAB;
            unsigned long long gu[6];
            #pragma unroll
            for (int jf = 0; jf < 6; ++jf)
                gu[jf] = load_sc8(slab + ((jf * 8 + w) * 64 + lane) * 4);

            if (t == 0) {
                const float* hr = h_in + (size_t)bw * 2 * H_ + H_;
                #pragma unroll
                for (int kc = 0; kc < 16; ++kc) {
                    short8 bf = z ? zed : cvt8v(*(const f32x4*)(hr + kc * 32 + kg),
                                                *(const f32x4*)(hr + kc * 32 + kg + 4));
                    chunk6<KP_, 4>(wlds, l15, kg, kc, bf, acc);
                }
            } else {
                const size_t tboff = (((size_t)((t - 1) & 3) * 32 + b16) * 16) * 512 + lane * 8;
                if (usel2) gather16<true, 4>(h1l2 + tboff, wlds, l15, kg, z, acc);
                else       gather16<false, 4>(h1l3 + tboff, wlds, l15, kg, z, acc);
            }

            const size_t hwoff = (((size_t)(t & 3) * 32 + b16) * 16 + jp) * 512;
            #pragma unroll
            for (int jh = 0; jh < 2; ++jh) {
                const int j4 = jb + jh * 16 + qr4;
                const f32x4 giR = unpk(gu[jh]);
                const f32x4 giZ = unpk(gu[2 + jh]);
                const f32x4 giN = unpk(gu[4 + jh]);
                f32x4 hv;
                #pragma unroll
                for (int r = 0; r < 4; ++r) {
                    const float rr = sigm(giR[r] + acc[jh][r] + bR[jh][r]);
                    const float zz = sigm(giZ[r] + acc[2 + jh][r] + bZ[jh][r]);
                    const float nn = tanhf(giN[r] + bIN[jh][r] + rr * (acc[4 + jh][r] + bHN[jh][r]));
                    const float hprev = z ? 0.0f : hp[jh][r];
                    hv[r] = (1.0f - zz) * nn + zz * hprev;
                }
                hp[jh] = hv;
                union { unsigned short us[4]; unsigned long long u; } pk;
                pk.us[0] = f2bf(hv[0]); pk.us[1] = f2bf(hv[1]);
                pk.us[2] = f2bf(hv[2]); pk.us[3] = f2bf(hv[3]);
                const int qp = jh * 2 + (q >> 1);
                const size_t eo = hwoff + (qp * 16 + l15) * 8 + (q & 1) * 4;
                *(unsigned long long*)(h1l2 + eo) = pk.u;
                store_sc8u(h1l3 + eo, pk.u);
                *(f32x4*)&out[((size_t)bw * T_ + t) * H_ + j4] = hv;
                if (t == T_ - 1)
                    *(f32x4*)&out[OUT_MAIN + (size_t)bw * 2 * H_ + H_ + j4] = hv;
            }
            __syncthreads();
            if (tid == 0) {
                lfh1[bt * 4096 + t * 16 + jp] = 1;
                __hip_atomic_store(&gfh1[(t * 4 + bt) * 16 + jp], 1, __ATOMIC_RELAXED, __HIP_MEMORY_SCOPE_AGENT);
            }
        }
    }
}

extern "C" void kernel_launch(void* const* d_in, const int* in_sizes, int n_in,
                              void* d_out, int out_size, void* d_ws, size_t ws_size,
                              hipStream_t stream) {
    (void)in_sizes; (void)n_in; (void)out_size; (void)ws_size;
    const float* x    = (const float*)d_in[0];
    const int*   isin = (const int*)d_in[1];
    const float* h_in = (const float*)d_in[2];
    const float* wih0 = (const float*)d_in[3];
    const float* whh0 = (const float*)d_in[4];
    const float* bih0 = (const float*)d_in[5];
    const float* bhh0 = (const float*)d_in[6];
    const float* wih1 = (const float*)d_in[7];
    const float* whh1 = (const float*)d_in[8];
    const float* bih1 = (const float*)d_in[9];
    const float* bhh1 = (const float*)d_in[10];
    float* out = (float*)d_out;
    char* ws = (char*)d_ws;

    init_kernel<<<dim3(256), dim3(256), 0, stream>>>((int*)(ws + OFF_FLG));

    gru_x<<<dim3(256), dim3(512), 0, stream>>>(
        x, isin, h_in,
        wih0, whh0, bih0, bhh0,
        wih1, whh1, bih1, bhh1,
        ws, out);
}

// Round 12
// 1352.991 us; speedup vs baseline: 29.0569x; 29.0569x over previous
//
#include <hip/hip_runtime.h>
#include <hip/hip_bf16.h>

#define B_ 512
#define T_ 128
#define DIN_ 256
#define H_ 512
#define KP_ 520             // LDS stride (bf16) K=512 weights
#define KP0_ 264            // LDS stride K=256 (wih0)
#define OUT_MAIN ((size_t)B_ * T_ * H_)
#define GISLAB 12288

// ws byte offsets
#define OFF_H1  2097152ull
#define OFF_GI1 4194304ull
#define OFF_FLG 16777216ull

typedef __attribute__((ext_vector_type(8))) short short8;
typedef __attribute__((ext_vector_type(4))) float f32x4;

__device__ __forceinline__ float sigm(float v) { return 1.0f / (1.0f + __expf(-v)); }

__device__ __forceinline__ unsigned short f2bf(float f) {
    union { __hip_bfloat16 b; unsigned short u; } c;
    c.b = __float2bfloat16(f);
    return c.u;
}

__device__ __forceinline__ short8 cvt8v(f32x4 u, f32x4 v) {
    short8 o;
    o[0] = (short)f2bf(u[0]); o[1] = (short)f2bf(u[1]);
    o[2] = (short)f2bf(u[2]); o[3] = (short)f2bf(u[3]);
    o[4] = (short)f2bf(v[0]); o[5] = (short)f2bf(v[1]);
    o[6] = (short)f2bf(v[2]); o[7] = (short)f2bf(v[3]);
    return o;
}

// coherent-point (sc0 sc1) 16B load — the proven cross-XCD transport
__device__ __forceinline__ short8 ldh(const __hip_bfloat16* p) {
    short8 r;
    asm volatile("global_load_dwordx4 %0, %1, off sc0 sc1" : "=v"(r) : "v"(p));
    return r;
}
#define VMWAIT(N) do { asm volatile("s_waitcnt vmcnt(" #N ")" ::: "memory"); \
                       __builtin_amdgcn_sched_barrier(0); } while (0)

__device__ __forceinline__ unsigned long long load_sc8(const __hip_bfloat16* p) {
    return __hip_atomic_load((const unsigned long long*)p, __ATOMIC_RELAXED, __HIP_MEMORY_SCOPE_AGENT);
}
__device__ __forceinline__ void store_sc8u(__hip_bfloat16* p, unsigned long long v) {
    __hip_atomic_store((unsigned long long*)p, v, __ATOMIC_RELAXED, __HIP_MEMORY_SCOPE_AGENT);
}
__device__ __forceinline__ void store_sc8(__hip_bfloat16* p, f32x4 h4) {
    union { unsigned short s[4]; unsigned long long u; } r;
    r.s[0] = f2bf(h4[0]); r.s[1] = f2bf(h4[1]);
    r.s[2] = f2bf(h4[2]); r.s[3] = f2bf(h4[3]);
    store_sc8u(p, r.u);
}

__device__ __forceinline__ f32x4 unpk(unsigned long long u) {
    f32x4 r;
    r[0] = __uint_as_float((unsigned)(u & 0xffffull) << 16);
    r[1] = __uint_as_float((unsigned)((u >> 16) & 0xffffull) << 16);
    r[2] = __uint_as_float((unsigned)((u >> 32) & 0xffffull) << 16);
    r[3] = __uint_as_float((unsigned)((u >> 48) & 0xffffull) << 16);
    return r;
}

// divergent per-lane poll on an agent flag (nullptr = no wait)
__device__ __forceinline__ void pollw(const int* p) {
    if (p)
        while (__hip_atomic_load(p, __ATOMIC_RELAXED, __HIP_MEMORY_SCOPE_AGENT) == 0)
            __builtin_amdgcn_s_sleep(1);
}

#define FIDX(t, bt, jp, w) (((((t) * 4 + (bt)) * 16 + (jp)) * 8) + (w))

__global__ void init_kernel(int* __restrict__ flg)
{
    int i = blockIdx.x * blockDim.x + threadIdx.x;
    int stride = gridDim.x * blockDim.x;
    for (int k = i; k < 196608; k += stride)
        __hip_atomic_store(&flg[k], 0, __ATOMIC_RELAXED, __HIP_MEMORY_SCOPE_AGENT);
}

// acc: 0,1 = r ; 2,3 = z ; NB,NB+1 = n
template<int KP, int NB>
__device__ __forceinline__ void chunk6(const __hip_bfloat16* wl, int l15, int kg, int kc,
                                       short8 bf, f32x4* acc) {
    #pragma unroll
    for (int g = 0; g < 3; ++g) {
        const int ai = (g == 2) ? NB : g * 2;
        #pragma unroll
        for (int jh = 0; jh < 2; ++jh) {
            short8 wf = *(const short8*)&wl[(size_t)(g * 32 + jh * 16 + l15) * KP + kc * 32 + kg];
            acc[ai + jh] = __builtin_amdgcn_mfma_f32_16x16x32_bf16(wf, bf, acc[ai + jh], 0, 0, 0);
        }
    }
}

// 16-deep pipelined gather of 16 x 1KB tiles (issue all, counted drains)
template<int NB>
__device__ __forceinline__ void gather16d(const __hip_bfloat16* tb, const __hip_bfloat16* wl,
                                          int l15, int kg, bool z, f32x4* acc)
{
    const short8 zed = {0,0,0,0,0,0,0,0};
    VMWAIT(0);   // honest vmcnt baseline (drains prior flag/slab ops)
    short8 v[16];
    #pragma unroll
    for (int i = 0; i < 16; ++i) v[i] = ldh(tb + i * 512);
    VMWAIT(12);
    #pragma unroll
    for (int i = 0; i < 4; ++i)  chunk6<KP_, NB>(wl, l15, kg, i, z ? zed : v[i], acc);
    VMWAIT(8);
    #pragma unroll
    for (int i = 4; i < 8; ++i)  chunk6<KP_, NB>(wl, l15, kg, i, z ? zed : v[i], acc);
    VMWAIT(4);
    #pragma unroll
    for (int i = 8; i < 12; ++i) chunk6<KP_, NB>(wl, l15, kg, i, z ? zed : v[i], acc);
    VMWAIT(0);
    #pragma unroll
    for (int i = 12; i < 16; ++i) chunk6<KP_, NB>(wl, l15, kg, i, z ? zed : v[i], acc);
}

// 256 blocks x 512 threads, stage = bid>>6: 0=R0 (gi0 local + gh0 + fuse -> h0),
// 1=R1 (gh1 + gi1 slab + fuse -> out), 2=G1 (gi1 = h0 @ wih1^T), 3=exit.
// bt=(bid>>4)&3, jp=bid&15. 8 waves = 8 disjoint 16-row groups; ALL dataflow is
// per-wave (flags [t][bt][jp][w]); no __syncthreads in the t-loop.
__global__ __launch_bounds__(512) void gru_wave(
    const float* __restrict__ x, const int* __restrict__ is_init,
    const float* __restrict__ h_in,
    const float* __restrict__ wih0, const float* __restrict__ whh0,
    const float* __restrict__ bih0, const float* __restrict__ bhh0,
    const float* __restrict__ wih1, const float* __restrict__ whh1,
    const float* __restrict__ bih1, const float* __restrict__ bhh1,
    char* __restrict__ ws, float* __restrict__ out)
{
    __shared__ __hip_bfloat16 wsh[96 * KP_ + 96 * KP0_];   // 150528 B

    const int bid = blockIdx.x;
    const int stage = bid >> 6;
    if (stage == 3) return;
    const int bt = (bid >> 4) & 3;
    const int jp = bid & 15;

    __hip_bfloat16* h0r = (__hip_bfloat16*)ws;                 // [4][32][16][512]
    __hip_bfloat16* h1r = (__hip_bfloat16*)(ws + OFF_H1);
    __hip_bfloat16* gi1 = (__hip_bfloat16*)(ws + OFF_GI1);     // [4][4][16][12288]
    int* flg  = (int*)(ws + OFF_FLG);
    int* fh0  = flg;
    int* fh1  = flg + 65536;
    int* fgi1 = flg + 131072;

    const int tid = threadIdx.x;
    const int lane = tid & 63;
    const int w = tid >> 6;
    const int l15 = lane & 15;
    const int q = lane >> 4;
    const int kg = q * 8;
    const int qr4 = q * 4;
    const int rb = bt * 128;
    const int jb = jp * 32;
    const int bw = rb + w * 16 + l15;
    const int b16 = bt * 8 + w;

    // ---- stage weights into LDS (f32 -> bf16), once ----
    __hip_bfloat16* wlds  = wsh;
    __hip_bfloat16* wlds2 = wsh + 96 * KP_;
    {
        const float* Wsrc = (stage == 0) ? whh0 : (stage == 1) ? whh1 : wih1;
        for (int idx = tid; idx < 96 * 64; idx += 512) {
            int gr = idx >> 6, c8 = idx & 63;
            int grow = (gr >> 5) * H_ + jb + (gr & 31);
            const float* p = Wsrc + (size_t)grow * H_ + c8 * 8;
            *(short8*)&wlds[(size_t)gr * KP_ + c8 * 8] = cvt8v(*(const f32x4*)p, *(const f32x4*)(p + 4));
        }
        if (stage == 0) {
            for (int idx = tid; idx < 96 * 32; idx += 512) {
                int gr = idx >> 5, c8 = idx & 31;
                int grow = (gr >> 5) * H_ + jb + (gr & 31);
                const float* p = wih0 + (size_t)grow * DIN_ + c8 * 8;
                *(short8*)&wlds2[(size_t)gr * KP0_ + c8 * 8] = cvt8v(*(const f32x4*)p, *(const f32x4*)(p + 4));
            }
        }
    }

    // ---- per-lane constants for R stages ----
    f32x4 bR[2], bZ[2], bIN[2], bHN[2], hp[2];
    if (stage < 2) {
        const float* bi = stage ? bih1 : bih0;
        const float* bh = stage ? bhh1 : bhh0;
        #pragma unroll
        for (int jh = 0; jh < 2; ++jh) {
            const int j4 = jb + jh * 16 + qr4;
            bR[jh]  = *(const f32x4*)&bi[j4]          + *(const f32x4*)&bh[j4];
            bZ[jh]  = *(const f32x4*)&bi[H_ + j4]     + *(const f32x4*)&bh[H_ + j4];
            bIN[jh] = *(const f32x4*)&bi[2 * H_ + j4];
            bHN[jh] = *(const f32x4*)&bh[2 * H_ + j4];
            hp[jh]  = *(const f32x4*)&h_in[(size_t)bw * 2 * H_ + (size_t)stage * H_ + j4];
        }
    }
    __syncthreads();   // LDS weights ready; last sync — waves free-run from here

    const short8 zed = {0, 0, 0, 0, 0, 0, 0, 0};

    for (int t = 0; t < T_; ++t) {
        if (stage == 0) {
            // ================= R0 =================
            f32x4 acc[8];
            #pragma unroll
            for (int i = 0; i < 8; ++i) acc[i] = f32x4{0.f, 0.f, 0.f, 0.f};
            const bool z = is_init[(size_t)bw * T_ + t] != 0;

            // gi0 = x @ wih0^T (independent -> before polls)
            const float* xr = x + ((size_t)bw * T_ + t) * DIN_;
            #pragma unroll
            for (int kc = 0; kc < 8; ++kc) {
                short8 bf = cvt8v(*(const f32x4*)(xr + kc * 32 + kg),
                                  *(const f32x4*)(xr + kc * 32 + kg + 4));
                chunk6<KP0_, 4>(wlds2, l15, kg, kc, bf, acc);
            }

            // per-wave dataflow waits
            {
                const int* p = nullptr;
                if (t > 0 && lane < 16)                       p = &fh0[FIDX(t - 1, bt, lane, w)];
                else if (t >= 4 && lane >= 32 && lane < 48)   p = &fgi1[FIDX(t - 4, bt, lane - 32, w)];
                pollw(p);
                asm volatile("" ::: "memory");
                __builtin_amdgcn_sched_barrier(0);
            }

            // gh0 over h0[t-1]
            if (t == 0) {
                const float* hr = h_in + (size_t)bw * 2 * H_;
                #pragma unroll
                for (int kc = 0; kc < 16; ++kc) {
                    short8 bf = z ? zed : cvt8v(*(const f32x4*)(hr + kc * 32 + kg),
                                                *(const f32x4*)(hr + kc * 32 + kg + 4));
                    chunk6<KP_, 6>(wlds, l15, kg, kc, bf, acc);
                }
            } else {
                const __hip_bfloat16* tb = h0r + (((size_t)((t - 1) & 3) * 32 + b16) * 16) * 512 + lane * 8;
                gather16d<6>(tb, wlds, l15, kg, z, acc);
            }

            // fuse + publish h0[t] (per-wave)
            __hip_bfloat16* hw = h0r + (((size_t)(t & 3) * 32 + b16) * 16 + jp) * 512;
            #pragma unroll
            for (int jh = 0; jh < 2; ++jh) {
                const int j4 = jb + jh * 16 + qr4;
                f32x4 hv;
                #pragma unroll
                for (int r = 0; r < 4; ++r) {
                    const float rr = sigm(acc[jh][r] + bR[jh][r]);
                    const float zz = sigm(acc[2 + jh][r] + bZ[jh][r]);
                    const float nn = tanhf(acc[4 + jh][r] + bIN[jh][r] + rr * (acc[6 + jh][r] + bHN[jh][r]));
                    const float hprev = z ? 0.0f : hp[jh][r];
                    hv[r] = (1.0f - zz) * nn + zz * hprev;
                }
                hp[jh] = hv;
                union { unsigned short us[4]; unsigned long long u; } pk;
                pk.us[0] = f2bf(hv[0]); pk.us[1] = f2bf(hv[1]);
                pk.us[2] = f2bf(hv[2]); pk.us[3] = f2bf(hv[3]);
                const int qp = jh * 2 + (q >> 1);
                store_sc8u(hw + (qp * 16 + l15) * 8 + (q & 1) * 4, pk.u);
                if (t == T_ - 1)
                    *(f32x4*)&out[OUT_MAIN + (size_t)bw * 2 * H_ + j4] = hv;
            }
            asm volatile("s_waitcnt vmcnt(0)" ::: "memory");
            __builtin_amdgcn_sched_barrier(0);
            if (lane == 0)
                __hip_atomic_store(&fh0[FIDX(t, bt, jp, w)], 1, __ATOMIC_RELAXED, __HIP_MEMORY_SCOPE_AGENT);
        } else if (stage == 2) {
            // ================= G1 =================
            f32x4 acc[6];
            #pragma unroll
            for (int i = 0; i < 6; ++i) acc[i] = f32x4{0.f, 0.f, 0.f, 0.f};
            {
                const int* p = nullptr;
                if (lane < 16)                        p = &fh0[FIDX(t, bt, lane, w)];
                else if (t >= 4 && lane == 16)        p = &fh1[FIDX(t - 4, bt, jp, w)];
                pollw(p);
                asm volatile("" ::: "memory");
                __builtin_amdgcn_sched_barrier(0);
            }
            const __hip_bfloat16* tb = h0r + (((size_t)(t & 3) * 32 + b16) * 16) * 512 + lane * 8;
            gather16d<4>(tb, wlds, l15, kg, false, acc);

            __hip_bfloat16* slab = gi1 + (((size_t)(t & 3) * 4 + bt) * 16 + jp) * GISLAB;
            #pragma unroll
            for (int jf = 0; jf < 6; ++jf)
                store_sc8(slab + ((jf * 8 + w) * 64 + lane) * 4, acc[jf]);
            asm volatile("s_waitcnt vmcnt(0)" ::: "memory");
            __builtin_amdgcn_sched_barrier(0);
            if (lane == 0)
                __hip_atomic_store(&fgi1[FIDX(t, bt, jp, w)], 1, __ATOMIC_RELAXED, __HIP_MEMORY_SCOPE_AGENT);
        } else {
            // ================= R1 =================
            f32x4 acc[6];
            #pragma unroll
            for (int i = 0; i < 6; ++i) acc[i] = f32x4{0.f, 0.f, 0.f, 0.f};
            const bool z = is_init[(size_t)bw * T_ + t] != 0;
            {
                const int* p = nullptr;
                if (t > 0 && lane < 16)   p = &fh1[FIDX(t - 1, bt, lane, w)];
                else if (lane == 16)      p = &fgi1[FIDX(t, bt, jp, w)];
                pollw(p);
                asm volatile("" ::: "memory");
                __builtin_amdgcn_sched_barrier(0);
            }
            const __hip_bfloat16* slab = gi1 + (((size_t)(t & 3) * 4 + bt) * 16 + jp) * GISLAB;
            unsigned long long gu[6];
            #pragma unroll
            for (int jf = 0; jf < 6; ++jf)
                gu[jf] = load_sc8(slab + ((jf * 8 + w) * 64 + lane) * 4);

            if (t == 0) {
                const float* hr = h_in + (size_t)bw * 2 * H_ + H_;
                #pragma unroll
                for (int kc = 0; kc < 16; ++kc) {
                    short8 bf = z ? zed : cvt8v(*(const f32x4*)(hr + kc * 32 + kg),
                                                *(const f32x4*)(hr + kc * 32 + kg + 4));
                    chunk6<KP_, 4>(wlds, l15, kg, kc, bf, acc);
                }
            } else {
                const __hip_bfloat16* tb = h1r + (((size_t)((t - 1) & 3) * 32 + b16) * 16) * 512 + lane * 8;
                gather16d<4>(tb, wlds, l15, kg, z, acc);
            }

            __hip_bfloat16* hw = h1r + (((size_t)(t & 3) * 32 + b16) * 16 + jp) * 512;
            #pragma unroll
            for (int jh = 0; jh < 2; ++jh) {
                const int j4 = jb + jh * 16 + qr4;
                const f32x4 giR = unpk(gu[jh]);
                const f32x4 giZ = unpk(gu[2 + jh]);
                const f32x4 giN = unpk(gu[4 + jh]);
                f32x4 hv;
                #pragma unroll
                for (int r = 0; r < 4; ++r) {
                    const float rr = sigm(giR[r] + acc[jh][r] + bR[jh][r]);
                    const float zz = sigm(giZ[r] + acc[2 + jh][r] + bZ[jh][r]);
                    const float nn = tanhf(giN[r] + bIN[jh][r] + rr * (acc[4 + jh][r] + bHN[jh][r]));
                    const float hprev = z ? 0.0f : hp[jh][r];
                    hv[r] = (1.0f - zz) * nn + zz * hprev;
                }
                hp[jh] = hv;
                union { unsigned short us[4]; unsigned long long u; } pk;
                pk.us[0] = f2bf(hv[0]); pk.us[1] = f2bf(hv[1]);
                pk.us[2] = f2bf(hv[2]); pk.us[3] = f2bf(hv[3]);
                const int qp = jh * 2 + (q >> 1);
                store_sc8u(hw + (qp * 16 + l15) * 8 + (q & 1) * 4, pk.u);
                *(f32x4*)&out[((size_t)bw * T_ + t) * H_ + j4] = hv;
                if (t == T_ - 1)
                    *(f32x4*)&out[OUT_MAIN + (size_t)bw * 2 * H_ + H_ + j4] = hv;
            }
            asm volatile("s_waitcnt vmcnt(0)" ::: "memory");
            __builtin_amdgcn_sched_barrier(0);
            if (lane == 0)
                __hip_atomic_store(&fh1[FIDX(t, bt, jp, w)], 1, __ATOMIC_RELAXED, __HIP_MEMORY_SCOPE_AGENT);
        }
    }
}

extern "C" void kernel_launch(void* const* d_in, const int* in_sizes, int n_in,
                              void* d_out, int out_size, void* d_ws, size_t ws_size,
                              hipStream_t stream) {
    (void)in_sizes; (void)n_in; (void)out_size; (void)ws_size;
    const float* x    = (const float*)d_in[0];
    const int*   isin = (const int*)d_in[1];
    const float* h_in = (const float*)d_in[2];
    const float* wih0 = (const float*)d_in[3];
    const float* whh0 = (const float*)d_in[4];
    const float* bih0 = (const float*)d_in[5];
    const float* bhh0 = (const float*)d_in[6];
    const float* wih1 = (const float*)d_in[7];
    const float* whh1 = (const float*)d_in[8];
    const float* bih1 = (const float*)d_in[9];
    const float* bhh1 = (const float*)d_in[10];
    float* out = (float*)d_out;
    char* ws = (char*)d_ws;

    init_kernel<<<dim3(256), dim3(256), 0, stream>>>((int*)(ws + OFF_FLG));

    gru_wave<<<dim3(256), dim3(512), 0, stream>>>(
        x, isin, h_in,
        wih0, whh0, bih0, bhh0,
        wih1, whh1, bih1, bhh1,
        ws, out);
}